// Round 11
// baseline (123.130 us; speedup 1.0000x reference)
//
#include <hip/hip_runtime.h>
#include <stdint.h>

typedef __bf16 bf16;
typedef __bf16 bf16x8 __attribute__((ext_vector_type(8)));
typedef __bf16 bf16x4 __attribute__((ext_vector_type(4)));
typedef float f32x4 __attribute__((ext_vector_type(4)));

constexpr int nB = 2, nS = 2048, nD = 768, nH = 12, nDK = 64;
constexpr int nM = nB * nS;  // 4096
constexpr float LN_EPS = 1e-5f;

static __device__ __forceinline__ f32x4 mfma16(bf16x8 a, bf16x8 b, f32x4 c) {
  return __builtin_amdgcn_mfma_f32_16x16x32_bf16(a, b, c, 0, 0, 0);
}

static __device__ __forceinline__ void gll16(const void* g, void* l) {
  __builtin_amdgcn_global_load_lds(
      (const __attribute__((address_space(1))) void*)g,
      (__attribute__((address_space(3))) void*)l, 16, 0, 0);
}

// ---------------- prep: x -> bf16 ----------------
__global__ __launch_bounds__(256) void k_prep_x(const float* __restrict__ x,
                                                bf16* __restrict__ xb) {
  int i = (blockIdx.x * 256 + threadIdx.x) * 4;
  float4 v = *(const float4*)(x + i);
  bf16x4 o;
  o[0] = (bf16)v.x; o[1] = (bf16)v.y; o[2] = (bf16)v.z; o[3] = (bf16)v.w;
  *(bf16x4*)(xb + i) = o;
}

// ---------------- prep: weights -> bf16, transposed to [n][k] ----------------
__global__ __launch_bounds__(256) void k_prep_w(
    const float* __restrict__ w0, const float* __restrict__ w1,
    const float* __restrict__ w2, const float* __restrict__ w3,
    const float* __restrict__ w4, bf16* __restrict__ wt) {
  __shared__ float tb[64][65];
  int w = blockIdx.z;
  const float* src = (w == 0) ? w0 : (w == 1) ? w1 : (w == 2) ? w2 : (w == 3) ? w3 : w4;
  int k0 = blockIdx.y * 64, n0 = blockIdx.x * 64;
  int tx = threadIdx.x & 63, ty = threadIdx.x >> 6;
#pragma unroll
  for (int it = 0; it < 16; ++it) {
    int r = it * 4 + ty;
    tb[r][tx] = src[(size_t)(k0 + r) * nD + n0 + tx];
  }
  __syncthreads();
  bf16* dst = wt + (size_t)w * nD * nD;
#pragma unroll
  for (int it = 0; it < 16; ++it) {
    int r = it * 4 + ty;
    dst[(size_t)(n0 + r) * nD + k0 + tx] = (bf16)tb[tx][r];
  }
}

// ---------------- QPKV GEMM: C = X @ W (Wt is W^T), 128x128 tile, BK=64 ----------------
__global__ __launch_bounds__(256, 2) void k_gemm_qpkv(
    const bf16* __restrict__ xb, const bf16* __restrict__ wt,
    bf16* __restrict__ qf, bf16* __restrict__ pf, bf16* __restrict__ kf_,
    bf16* __restrict__ vt) {
  __shared__ alignas(16) char smem[65536];  // [2 bufs][A 16K | B 16K]
  int t = threadIdx.x, lane = t & 63, w = t >> 6;
  int fr = lane & 15, fg = lane >> 4;
  int wm = w >> 1, wn = w & 1;
  int widx = blockIdx.z;
  int m0 = blockIdx.y * 128, n0 = blockIdx.x * 128;
  const bf16* abase = xb + (size_t)m0 * nD;
  const bf16* bbase = wt + (size_t)widx * nD * nD + (size_t)n0 * nD;

  f32x4 acc[4][4];
#pragma unroll
  for (int i = 0; i < 4; ++i)
#pragma unroll
    for (int j = 0; j < 4; ++j) acc[i][j] = (f32x4){0.f, 0.f, 0.f, 0.f};

  int aoff[2][4], boff[2][4];
#pragma unroll
  for (int ks = 0; ks < 2; ++ks) {
#pragma unroll
    for (int i = 0; i < 4; ++i) {
      int row = wm * 64 + i * 16 + fr;
      aoff[ks][i] = row * 128 + (((ks * 4 + fg) ^ (row & 7)) << 4);
      int rowb = wn * 64 + i * 16 + fr;
      boff[ks][i] = 16384 + rowb * 128 + (((ks * 4 + fg) ^ (rowb & 7)) << 4);
    }
  }
  const bf16 *asrc[4], *bsrc[4];
#pragma unroll
  for (int i = 0; i < 4; ++i) {
    int row = i * 32 + (t >> 3);
    int c = (t & 7) ^ (row & 7);
    asrc[i] = abase + (size_t)row * nD + c * 8;
    bsrc[i] = bbase + (size_t)row * nD + c * 8;
  }

#define STAGEG(BUF, kt)                                                        \
  {                                                                            \
    _Pragma("unroll") for (int i = 0; i < 4; ++i) {                            \
      gll16(asrc[i] + (kt)*64, smem + (BUF) + i * 4096 + w * 1024);            \
      gll16(bsrc[i] + (kt)*64, smem + (BUF) + 16384 + i * 4096 + w * 1024);    \
    }                                                                          \
  }

#define COMPUTEG(BUF)                                                          \
  {                                                                            \
    _Pragma("unroll") for (int ks = 0; ks < 2; ++ks) {                         \
      bf16x8 af[4], bfr[4];                                                    \
      _Pragma("unroll") for (int i = 0; i < 4; ++i)                            \
          af[i] = *(const bf16x8*)(smem + (BUF) + aoff[ks][i]);                \
      _Pragma("unroll") for (int j = 0; j < 4; ++j)                            \
          bfr[j] = *(const bf16x8*)(smem + (BUF) + boff[ks][j]);               \
      _Pragma("unroll") for (int i = 0; i < 4; ++i)                            \
          _Pragma("unroll") for (int j = 0; j < 4; ++j) acc[i][j] =            \
          mfma16(af[i], bfr[j], acc[i][j]);                                    \
    }                                                                          \
  }

  STAGEG(0, 0);
  __syncthreads();
#pragma unroll 1
  for (int kt = 0; kt < 12; kt += 2) {
    if (kt + 1 < 12) STAGEG(32768, kt + 1);
    COMPUTEG(0);
    __syncthreads();
    if (kt + 2 < 12) STAGEG(0, kt + 2);
    COMPUTEG(32768);
    __syncthreads();
  }
#undef STAGEG
#undef COMPUTEG

  if (widx < 3) {
    bf16* outf = (widx == 0) ? qf : (widx == 1) ? pf : kf_;
    float oscale = (widx == 2) ? 0.18033688f : 1.0f;  // K: DK^-0.5 * log2(e)
#pragma unroll
    for (int i = 0; i < 4; ++i)
#pragma unroll
      for (int j = 0; j < 4; ++j) {
        int n = n0 + wn * 64 + j * 16 + fr;
#pragma unroll
        for (int r = 0; r < 4; ++r) {
          int m = m0 + wm * 64 + i * 16 + fg * 4 + r;
          outf[(size_t)m * nD + n] = (bf16)(acc[i][j][r] * oscale);
        }
      }
  } else {
#pragma unroll
    for (int i = 0; i < 4; ++i)
#pragma unroll
      for (int j = 0; j < 4; ++j) {
        int n = n0 + wn * 64 + j * 16 + fr;
        int h = n >> 6, dk = n & 63;
        int mbase = m0 + wm * 64 + i * 16 + fg * 4;
        int b = mbase >> 11, s = mbase & (nS - 1);
        int bh = b * nH + h;
        bf16x4 pk;
#pragma unroll
        for (int r = 0; r < 4; ++r) pk[r] = (bf16)acc[i][j][r];
        *(bf16x4*)(vt + ((size_t)bh * nDK + dk) * nS + s) = pk;
      }
  }
}

// ---------------- attention pass 1 + leapfrog -> q_new ----------------
// 2q-group amortized structure: wave = 32 q (two 16x16 fragments), 64-key
// tiles. K/V LDS fragment reads (16KB/tile) are SHARED across both q-groups
// -> LDS bytes per q nearly halved vs R10 (28KB per 32q vs 24KB per 16q).
// Block = 2 waves = 64 q; grid unchanged (768 = 3 blocks/CU, 6 waves/CU).
// All offsets hoisted; counted vmcnt(8); unnormalized exp2 softmax with
// in-register all-ones MFMA row-sum; K pre-scaled to exp2 domain.
__global__ __launch_bounds__(128, 2) void k_attn(
    const bf16* __restrict__ qf, const bf16* __restrict__ pf,
    const bf16* __restrict__ kf_, const bf16* __restrict__ vt,
    const float* __restrict__ dtp, const float* __restrict__ gatep,
    bf16* __restrict__ qn) {
  // LDS: K dbuf @0/@8192 | V dbuf @16384/@24576 | P @32768: w*4096+qg*2048
  __shared__ alignas(16) char lds[40960];
  int t = threadIdx.x, lane = t & 63, w = t >> 6;  // w in {0,1}
  int fr = lane & 15, fg = lane >> 4;
  int blk = blockIdx.x;
  int qt = blk & 31, bh = blk >> 5;
  int b = bh / nH, h = bh % nH;
  int q0 = qt * 64 + w * 32;
  const bf16* Qrow = qf + (size_t)(b * nS) * nD + (size_t)h * nDK;
  const bf16* Prow = pf + (size_t)(b * nS) * nD + (size_t)h * nDK;
  const bf16* Krow = kf_ + (size_t)(b * nS) * nD + (size_t)h * nDK;
  const bf16* Vb = vt + (size_t)bh * nDK * nS;
  char* myp = lds + 32768 + w * 4096;

  bf16x8 qa[2][2];
#pragma unroll
  for (int qg = 0; qg < 2; ++qg)
#pragma unroll
    for (int ks = 0; ks < 2; ++ks)
      qa[qg][ks] = *(const bf16x8*)(Qrow + (size_t)(q0 + qg * 16 + fr) * nD +
                                    ks * 32 + fg * 8);

  bf16x8 vone;
#pragma unroll
  for (int i = 0; i < 8; ++i) vone[i] = (bf16)1.0f;

  f32x4 o[2][5];  // o[qg][0..3]: O^T[dv][q]; o[qg][4]: row-sum lr
#pragma unroll
  for (int qg = 0; qg < 2; ++qg)
#pragma unroll
    for (int df = 0; df < 5; ++df) o[qg][df] = (f32x4){0.f, 0.f, 0.f, 0.f};

  // ---- hoisted LDS read/write offsets (bytes, loop-invariant) ----
  int koA[4], koB[4];
#pragma unroll
  for (int kfi = 0; kfi < 4; ++kfi) {
    int key = kfi * 16 + fr;
    koA[kfi] = key * 128 + ((fg ^ (key & 7)) << 4);
    koB[kfi] = key * 128 + (((4 + fg) ^ (key & 7)) << 4);
  }
  int vo[2][4], pr[2], pw[4];
#pragma unroll
  for (int ks = 0; ks < 2; ++ks) {
    pr[ks] = fr * 128 + (((ks * 4 + fg) ^ (fr & 7)) << 4);
#pragma unroll
    for (int df = 0; df < 4; ++df) {
      int row = df * 16 + fr;
      vo[ks][df] = row * 128 + (((ks * 4 + fg) ^ (row & 7)) << 4);
    }
  }
#pragma unroll
  for (int kfi = 0; kfi < 4; ++kfi) {
    int blk16 = kfi * 2 + (fg >> 1);
    pw[kfi] = fr * 128 + (((blk16 ^ (fr & 7)) << 4) | ((fg & 1) << 3));
  }

  // ---- hoisted staging sources: wave w stages rows [w*32, w*32+32) ----
  // row = w*32 + i*8 + (lane>>3); row&7 == lane>>3 -> chunk swizzle is
  // loop-invariant: c = (lane&7) ^ (lane>>3).
  const bf16 *ksrc[4], *vsrc[4];
  {
    int c = (lane & 7) ^ (lane >> 3);
#pragma unroll
    for (int i = 0; i < 4; ++i) {
      int row = w * 32 + i * 8 + (lane >> 3);
      ksrc[i] = Krow + (size_t)row * nD + c * 8;
      vsrc[i] = Vb + (size_t)row * nS + c * 8;
    }
  }

#define STAGE(KB, VB, kt)                                                      \
  {                                                                            \
    _Pragma("unroll") for (int i = 0; i < 4; ++i) {                            \
      gll16(ksrc[i] + (size_t)(kt)*64 * nD, lds + (KB) + w * 4096 + i * 1024); \
      gll16(vsrc[i] + (kt)*64, lds + (VB) + w * 4096 + i * 1024);              \
    }                                                                          \
  }

#define COMPUTE(KB, VB)                                                        \
  {                                                                            \
    f32x4 sf[2][4];                                                            \
    _Pragma("unroll") for (int kfi = 0; kfi < 4; ++kfi) {                      \
      bf16x8 ka = *(const bf16x8*)(lds + (KB) + koA[kfi]);                     \
      bf16x8 kc = *(const bf16x8*)(lds + (KB) + koB[kfi]);                     \
      _Pragma("unroll") for (int qg = 0; qg < 2; ++qg) {                       \
        f32x4 s = mfma16(ka, qa[qg][0], (f32x4){0.f, 0.f, 0.f, 0.f});          \
        sf[qg][kfi] = mfma16(kc, qa[qg][1], s);                                \
      }                                                                        \
    }                                                                          \
    _Pragma("unroll") for (int qg = 0; qg < 2; ++qg)                           \
        _Pragma("unroll") for (int kfi = 0; kfi < 4; ++kfi) {                  \
      bf16x4 pk;                                                               \
      _Pragma("unroll") for (int r = 0; r < 4; ++r)                            \
          pk[r] = (bf16)__builtin_exp2f(sf[qg][kfi][r]);                       \
      *(bf16x4*)(myp + qg * 2048 + pw[kfi]) = pk;                              \
    }                                                                          \
    _Pragma("unroll") for (int ks = 0; ks < 2; ++ks) {                         \
      bf16x8 vv[4];                                                            \
      _Pragma("unroll") for (int df = 0; df < 4; ++df)                         \
          vv[df] = *(const bf16x8*)(lds + (VB) + vo[ks][df]);                  \
      _Pragma("unroll") for (int qg = 0; qg < 2; ++qg) {                       \
        bf16x8 pb = *(const bf16x8*)(myp + qg * 2048 + pr[ks]);                \
        _Pragma("unroll") for (int df = 0; df < 4; ++df)                       \
            o[qg][df] = mfma16(vv[df], pb, o[qg][df]);                         \
        o[qg][4] = mfma16(vone, pb, o[qg][4]);                                 \
      }                                                                        \
    }                                                                          \
  }

#define VMCNT8 asm volatile("s_waitcnt vmcnt(8)" ::: "memory")
#define VMCNT0 asm volatile("s_waitcnt vmcnt(0)" ::: "memory")
#define BAR __builtin_amdgcn_s_barrier()

  STAGE(0, 16384, 0);
#pragma unroll 1
  for (int kt = 0; kt < 32; kt += 2) {
    STAGE(8192, 24576, kt + 1);  // prefetch stays in flight across barrier
    VMCNT8;                      // wait current buf's 8 loads only
    BAR;
    COMPUTE(0, 16384);
    BAR;
    if (kt + 2 < 32) {
      STAGE(0, 16384, kt + 2);
      VMCNT8;
    } else {
      VMCNT0;
    }
    BAR;
    COMPUTE(8192, 24576);
    BAR;
  }
#undef STAGE
#undef COMPUTE
#undef VMCNT8
#undef VMCNT0
#undef BAR

  // leapfrog: q_new = q + dt*p - (dt^2/2)*gate*pe1
  float dt = dtp[0], gate = gatep[0];
  float c2 = 0.5f * dt * dt * gate;
#pragma unroll
  for (int qg = 0; qg < 2; ++qg) {
    float inv = 1.f / o[qg][4][0];  // lr, same in every lane sharing this q
    int qrow = q0 + qg * 16 + fr;
#pragma unroll
    for (int df = 0; df < 4; ++df) {
      int dk = df * 16 + fg * 4;
      bf16x4 qv4 = *(const bf16x4*)(Qrow + (size_t)qrow * nD + dk);
      bf16x4 pv4 = *(const bf16x4*)(Prow + (size_t)qrow * nD + dk);
      bf16x4 ov;
#pragma unroll
      for (int r = 0; r < 4; ++r) {
        float pe = o[qg][df][r] * inv;
        ov[r] = (bf16)((float)qv4[r] + dt * (float)pv4[r] - c2 * pe);
      }
      *(bf16x4*)(qn + ((size_t)(b * nS) + qrow) * nD + h * nDK + dk) = ov;
    }
  }
}

// ---------------- output GEMM: outp = qn @ Wo + bo + x (f32) ----------------
__global__ __launch_bounds__(256, 2) void k_gemm_out(
    const bf16* __restrict__ qn, const bf16* __restrict__ wto,
    const float* __restrict__ bo, const float* __restrict__ x,
    float* __restrict__ outp) {
  __shared__ alignas(16) char smem[65536];
  int t = threadIdx.x, lane = t & 63, w = t >> 6;
  int fr = lane & 15, fg = lane >> 4;
  int wm = w >> 1, wn = w & 1;
  int m0 = blockIdx.y * 128, n0 = blockIdx.x * 128;
  const bf16* abase = qn + (size_t)m0 * nD;
  const bf16* bbase = wto + (size_t)n0 * nD;

  f32x4 acc[4][4];
#pragma unroll
  for (int i = 0; i < 4; ++i)
#pragma unroll
    for (int j = 0; j < 4; ++j) acc[i][j] = (f32x4){0.f, 0.f, 0.f, 0.f};

  int aoff[2][4], boff[2][4];
#pragma unroll
  for (int ks = 0; ks < 2; ++ks) {
#pragma unroll
    for (int i = 0; i < 4; ++i) {
      int row = wm * 64 + i * 16 + fr;
      aoff[ks][i] = row * 128 + (((ks * 4 + fg) ^ (row & 7)) << 4);
      int rowb = wn * 64 + i * 16 + fr;
      boff[ks][i] = 16384 + rowb * 128 + (((ks * 4 + fg) ^ (rowb & 7)) << 4);
    }
  }
  const bf16 *asrc[4], *bsrc[4];
#pragma unroll
  for (int i = 0; i < 4; ++i) {
    int row = i * 32 + (t >> 3);
    int c = (t & 7) ^ (row & 7);
    asrc[i] = abase + (size_t)row * nD + c * 8;
    bsrc[i] = bbase + (size_t)row * nD + c * 8;
  }

#define STAGEG(BUF, kt)                                                        \
  {                                                                            \
    _Pragma("unroll") for (int i = 0; i < 4; ++i) {                            \
      gll16(asrc[i] + (kt)*64, smem + (BUF) + i * 4096 + w * 1024);            \
      gll16(bsrc[i] + (kt)*64, smem + (BUF) + 16384 + i * 4096 + w * 1024);    \
    }                                                                          \
  }

#define COMPUTEG(BUF)                                                          \
  {                                                                            \
    _Pragma("unroll") for (int ks = 0; ks < 2; ++ks) {                         \
      bf16x8 af[4], bfr[4];                                                    \
      _Pragma("unroll") for (int i = 0; i < 4; ++i)                            \
          af[i] = *(const bf16x8*)(smem + (BUF) + aoff[ks][i]);                \
      _Pragma("unroll") for (int j = 0; j < 4; ++j)                            \
          bfr[j] = *(const bf16x8*)(smem + (BUF) + boff[ks][j]);               \
      _Pragma("unroll") for (int i = 0; i < 4; ++i)                            \
          _Pragma("unroll") for (int j = 0; j < 4; ++j) acc[i][j] =            \
          mfma16(af[i], bfr[j], acc[i][j]);                                    \
    }                                                                          \
  }

  STAGEG(0, 0);
  __syncthreads();
#pragma unroll 1
  for (int kt = 0; kt < 12; kt += 2) {
    if (kt + 1 < 12) STAGEG(32768, kt + 1);
    COMPUTEG(0);
    __syncthreads();
    if (kt + 2 < 12) STAGEG(0, kt + 2);
    COMPUTEG(32768);
    __syncthreads();
  }
#undef STAGEG
#undef COMPUTEG

#pragma unroll
  for (int i = 0; i < 4; ++i)
#pragma unroll
    for (int j = 0; j < 4; ++j) {
      int n = n0 + wn * 64 + j * 16 + fr;
      float bias = bo[n];
#pragma unroll
      for (int r = 0; r < 4; ++r) {
        int m = m0 + wm * 64 + i * 16 + fg * 4 + r;
        outp[(size_t)m * nD + n] = acc[i][j][r] + bias + x[(size_t)m * nD + n];
      }
    }
}

// ---------------- LayerNorm (in-place on d_out), one wave per row ----------------
__global__ __launch_bounds__(256) void k_ln(const float* outp,
                                            const float* __restrict__ gamma,
                                            const float* __restrict__ beta,
                                            float* y) {
  int t = threadIdx.x, lane = t & 63, w = t >> 6;
  int row = blockIdx.x * 4 + w;
  const float* rp = outp + (size_t)row * nD;
  float v[12], s1 = 0.f, s2 = 0.f;
#pragma unroll
  for (int i = 0; i < 12; ++i) {
    v[i] = rp[lane + i * 64];
    s1 += v[i];
    s2 += v[i] * v[i];
  }
#pragma unroll
  for (int d = 1; d < 64; d <<= 1) {
    s1 += __shfl_xor(s1, d);
    s2 += __shfl_xor(s2, d);
  }
  float mu = s1 * (1.f / 768.f);
  float var = s2 * (1.f / 768.f) - mu * mu;
  float rstd = rsqrtf(var + LN_EPS);
  float* yp = y + (size_t)row * nD;
#pragma unroll
  for (int i = 0; i < 12; ++i) {
    int n = lane + i * 64;
    yp[n] = (v[i] - mu) * rstd * gamma[n] + beta[n];
  }
}

extern "C" void kernel_launch(void* const* d_in, const int* in_sizes, int n_in,
                              void* d_out, int out_size, void* d_ws, size_t ws_size,
                              hipStream_t stream) {
  const float* x = (const float*)d_in[0];
  const float* Wq = (const float*)d_in[1];
  const float* Wp = (const float*)d_in[2];
  const float* Wk = (const float*)d_in[3];
  const float* Wv = (const float*)d_in[4];
  const float* Wo = (const float*)d_in[5];
  const float* bo = (const float*)d_in[6];
  const float* gamma = (const float*)d_in[7];
  const float* beta = (const float*)d_in[8];
  const float* dt = (const float*)d_in[9];
  const float* gate = (const float*)d_in[10];

  char* ws = (char*)d_ws;
  const size_t szb = (size_t)nM * nD * 2;  // 6,291,456 bytes per bf16 [4096][768]
  bf16* xb = (bf16*)(ws + 0 * szb);        // reused as qn after QPKV GEMM
  bf16* qf = (bf16*)(ws + 1 * szb);
  bf16* pf = (bf16*)(ws + 2 * szb);
  bf16* kf_ = (bf16*)(ws + 3 * szb);
  bf16* vt = (bf16*)(ws + 4 * szb);
  bf16* wt = (bf16*)(ws + 5 * szb);  // 5 * 768*768 bf16 = 5,898,240 bytes
  bf16* qn = xb;
  float* outp = (float*)d_out;  // out-GEMM result, LN runs in place

  k_prep_x<<<dim3(nM * nD / 1024), dim3(256), 0, stream>>>(x, xb);
  k_prep_w<<<dim3(12, 12, 5), dim3(256), 0, stream>>>(Wq, Wp, Wk, Wv, Wo, wt);
  k_gemm_qpkv<<<dim3(6, 32, 4), dim3(256), 0, stream>>>(xb, wt, qf, pf, kf_, vt);
  k_attn<<<dim3(768), dim3(128), 0, stream>>>(qf, pf, kf_, vt, dt, gate, qn);
  k_gemm_out<<<dim3(6, 32), dim3(256), 0, stream>>>(qn, wt + 4 * (size_t)nD * nD, bo, x, outp);
  k_ln<<<dim3(nM / 4), dim3(256), 0, stream>>>(outp, gamma, beta, (float*)d_out);
}